// Round 6
// baseline (80.767 us; speedup 1.0000x reference)
//
#include <hip/hip_runtime.h>

#define NB     32
#define NATOM  48
#define NGRID  128
#define KT     16                         /* grid points per block */
#define NTHR   384                        /* 6 waves: thread = (n, kq) */

#define MBTR_ELEMS (NB*16*NGRID)          /* 65536 */
#define DIV_PER_B  (16*NGRID*NATOM*3)     /* 294912 */
#define PANE       (NGRID*NATOM*3)        /* 18432 floats per (e1,e2) pane */
#define MSTRIDE    49                     /* padded n-stride for M table */

// Fused MBTR fwd+div, register-direct output, 2-k-per-thread.
// Phase 1: thread = (n, kq in 0..7) accumulates grid points k0+kq and
// k0+kq+8. Pair geometry (diff, d2, rsq, folded-exponent base, bq, u) is
// computed ONCE per m and shared by both k's. Species-SEGMENTED loop keeps
// the accumulator index e STATIC (R4 lesson: runtime-e indexing forces
// cndmask/scratch, +9us). wf and coef folded into the exp2 argument;
// self-pair killed via base=1e30.
// Order matters: mbtr reduction (needs __syncthreads for the LDS M table)
// runs BEFORE the 96 global div stores, so the barrier's implicit
// s_waitcnt vmcnt(0) does not drain the store queue (R5 had stores first).
// Div stores are float3 -> global_store_dwordx3, 3x fewer store instrs.
__global__ __launch_bounds__(NTHR)
void mbtr_fused(const float* __restrict__ r, const int* __restrict__ z,
                const float* __restrict__ grid, float* __restrict__ out)
{
    const int kt = blockIdx.x, b = blockIdx.y, t = threadIdx.x;
    const int k0 = kt * KT;

    __shared__ float4 pos[NATOM];
    __shared__ int    zl[NATOM];
    __shared__ int    order[NATOM];
    __shared__ int    soff_s[5];
    __shared__ float  Mrec[KT * 4 * MSTRIDE];   /* [kk][e][49] */

    // ---- setup: wave 0 loads atoms, builds species-sorted order ----
    if (t < 64) {
        const bool isatom = (t < NATOM);
        int myz = 999;
        if (isatom) {
            myz = z[t];
            zl[t] = myz;
            const float* rp = r + ((size_t)b * NATOM + t) * 3;
            pos[t] = make_float4(rp[0], rp[1], rp[2], 0.f);
        }
        const unsigned long long m0 = __ballot(myz == 0);
        const unsigned long long m1 = __ballot(myz == 1);
        const unsigned long long m2 = __ballot(myz == 2);
        const unsigned long long m3 = __ballot(myz == 3);
        const int c0 = __popcll(m0), c1 = __popcll(m1), c2 = __popcll(m2);
        if (isatom) {
            const unsigned long long mm = (myz == 0) ? m0 : (myz == 1) ? m1
                                        : (myz == 2) ? m2 : m3;
            const int base = (myz == 0) ? 0 : (myz == 1) ? c0
                           : (myz == 2) ? c0 + c1 : c0 + c1 + c2;
            const int rank = __popcll(mm & ((1ull << t) - 1ull));
            order[base + rank] = t;
        }
        if (t == 0) {
            soff_s[0] = 0; soff_s[1] = c0; soff_s[2] = c0 + c1;
            soff_s[3] = c0 + c1 + c2; soff_s[4] = NATOM;
        }
    }
    __syncthreads();

    // ---- phase 1: thread = (n, kq), grid points k0+kq and k0+kq+8 ----
    const int n  = t % NATOM;
    const int kq = t / NATOM;               // 0..7
    const float dx   = grid[1] - grid[0];
    const float coef = dx * 7.9788456080286535f;     // dx*20/sqrt(2pi)
    const float mlc  = -__log2f(coef);
    const float isc  = 16.986436005760382f;          // 20*sqrt(log2e/2)
    const float tBc  = 23.548200452219559f;          // 20/sqrt(log2e/2)
    const float l2e  = 1.4426950408889634f;
    const float gkA  = grid[k0 + kq]     * isc;
    const float gkB  = grid[k0 + kq + 8] * isc;

    float A[2][4][3] = {{{0.f}}};
    float M[2][4]    = {{0.f}};
    const float4 rn = pos[n];
    const int   zn  = zl[n];
    int so[5];
    #pragma unroll
    for (int e = 0; e < 5; ++e) so[e] = soff_s[e];

    #pragma unroll
    for (int e = 0; e < 4; ++e) {           // e STATIC -> A[.][e] in regs
        for (int i = so[e]; i < so[e + 1]; ++i) {
            const int    m  = order[i];     // uniform -> broadcast
            const float4 rm = pos[m];       // uniform -> broadcast
            const float ddx = rn.x - rm.x, ddy = rn.y - rm.y, ddz = rn.z - rm.z;
            float d2 = ddx*ddx + ddy*ddy + ddz*ddz;
            const bool self = (m == n);
            d2 = self ? 1.0f : d2;                        // rsq NaN guard
            const float gf  = __builtin_amdgcn_rsqf(d2);  // 1/d
            const float c1  = gf * isc;
            const float d   = d2 * gf;
            float base = fmaf(d, l2e, mlc);               // wf & coef folded
            base = self ? 1e30f : base;                   // kill self pair
            const float bq  = (gf * gf) * tBc;
            const float sux = gf * ddx, suy = gf * ddy, suz = gf * ddz;
            {   // k = k0 + kq
                const float tt = gkA - c1;
                const float ex = exp2f(-fmaf(tt, tt, base));  // coef*wf*gv
                M[0][e] += ex;
                const float p  = ex * fmaf(tt, bq, 1.0f);
                A[0][e][0] = fmaf(-p, sux, A[0][e][0]);
                A[0][e][1] = fmaf(-p, suy, A[0][e][1]);
                A[0][e][2] = fmaf(-p, suz, A[0][e][2]);
            }
            {   // k = k0 + kq + 8
                const float tt = gkB - c1;
                const float ex = exp2f(-fmaf(tt, tt, base));
                M[1][e] += ex;
                const float p  = ex * fmaf(tt, bq, 1.0f);
                A[1][e][0] = fmaf(-p, sux, A[1][e][0]);
                A[1][e][1] = fmaf(-p, suy, A[1][e][1]);
                A[1][e][2] = fmaf(-p, suz, A[1][e][2]);
            }
        }
    }

    {   // M table to LDS
        float* mr0 = Mrec + kq       * (4 * MSTRIDE) + n;
        float* mr1 = Mrec + (kq + 8) * (4 * MSTRIDE) + n;
        #pragma unroll
        for (int e = 0; e < 4; ++e) {
            mr0[e * MSTRIDE] = M[0][e];
            mr1[e * MSTRIDE] = M[1][e];
        }
    }
    __syncthreads();    // drains LDS only: no global stores in flight yet

    // ---- phase 2a: mbtr reduction (threads 0..255: one (pane,kk) each) ----
    if (t < 256) {
        const int mpane = t >> 4, mkk = t & 15;
        const int me1 = mpane >> 2, me2 = mpane & 3;
        const float* tr2 = Mrec + mkk * (4 * MSTRIDE) + me2 * MSTRIDE;
        float s = 0.f;
        #pragma unroll
        for (int nn = 0; nn < NATOM; ++nn)
            s += (zl[nn] == me1) ? tr2[nn] : 0.f;
        out[(size_t)b * 2048 + mpane * NGRID + k0 + mkk] = s;
    }

    // ---- phase 2b: div writes straight from registers (dwordx3) ----
    // pane (e1,e2) value at (n,c) = (zn==e1)*A[e2][c] + (zn==e2)*A[e1][c]
    float* divout = out + MBTR_ELEMS + (size_t)b * DIV_PER_B;
    #pragma unroll
    for (int h = 0; h < 2; ++h) {
        float* basep = divout + (size_t)(k0 + kq + 8 * h) * 144 + n * 3;
        #pragma unroll
        for (int e1 = 0; e1 < 4; ++e1) {
            const bool s1 = (zn == e1);
            #pragma unroll
            for (int e2 = 0; e2 < 4; ++e2) {
                const bool s2 = (zn == e2);
                float3 v;
                v.x = (s1 ? A[h][e2][0] : 0.f) + (s2 ? A[h][e1][0] : 0.f);
                v.y = (s1 ? A[h][e2][1] : 0.f) + (s2 ? A[h][e1][1] : 0.f);
                v.z = (s1 ? A[h][e2][2] : 0.f) + (s2 ? A[h][e1][2] : 0.f);
                *(float3*)(basep + (e1 * 4 + e2) * PANE) = v;
            }
        }
    }
}

extern "C" void kernel_launch(void* const* d_in, const int* in_sizes, int n_in,
                              void* d_out, int out_size, void* d_ws, size_t ws_size,
                              hipStream_t stream)
{
    const float* r    = (const float*)d_in[0];
    const int*   z    = (const int*)  d_in[1];
    const float* grid = (const float*)d_in[2];
    float* out = (float*)d_out;
    (void)d_ws; (void)ws_size;

    mbtr_fused<<<dim3(NGRID / KT, NB), NTHR, 0, stream>>>(r, z, grid, out);
}